// Round 1
// baseline (3976.153 us; speedup 1.0000x reference)
//
#include <hip/hip_runtime.h>

#define N_NODES 100000
#define E_EDGES 1600000
#define HDIM 64
#define OCDIM 16
#define KCHEB 4
#define BN_EPS 1e-5f

// ---------------------------------------------------------------- degree
__global__ void deg_kernel(const int* __restrict__ src, float* __restrict__ deg) {
    int e = blockIdx.x * blockDim.x + threadIdx.x;
    if (e < E_EDGES) atomicAdd(&deg[src[e]], 1.0f);
}

__global__ void dinv_kernel(float* deg) {
    int i = blockIdx.x * blockDim.x + threadIdx.x;
    if (i < N_NODES) {
        float d = deg[i];
        deg[i] = (d > 0.0f) ? 1.0f / sqrtf(fmaxf(d, 1.0f)) : 0.0f;
    }
}

// ---------------------------------------------------------------- propagation
// out[dst] += scale * w_e * x[src],  w_e = -dinv[src]*dinv[dst]
// One 64-lane wave per edge; lane = feature. 4 edges per 256-thread block.
__global__ __launch_bounds__(256) void prop_kernel(
        const float* __restrict__ x, float* __restrict__ out,
        const int* __restrict__ src, const int* __restrict__ dst,
        const float* __restrict__ dinv, float scale) {
    int e = blockIdx.x * 4 + (threadIdx.x >> 6);
    int lane = threadIdx.x & 63;
    if (e >= E_EDGES) return;
    int s = src[e], d = dst[e];
    float w = -scale * dinv[s] * dinv[d];
    float v = w * x[s * HDIM + lane];
    atomicAdd(&out[d * HDIM + lane], v);
}

// out = -in   (init for T_k = 2*L*T_{k-1} - T_{k-2})
__global__ void copyneg_kernel(const float* __restrict__ in, float* __restrict__ out, int n4) {
    int i = blockIdx.x * blockDim.x + threadIdx.x;
    if (i >= n4) return;
    float4 v = reinterpret_cast<const float4*>(in)[i];
    reinterpret_cast<float4*>(out)[i] = make_float4(-v.x, -v.y, -v.z, -v.w);
}

// ---------------------------------------------------------------- combine: out = relu(BN(sum_k T_k@W_k + b))
__global__ __launch_bounds__(256) void combine_kernel(
        const float* __restrict__ T0, const float* __restrict__ T1,
        const float* __restrict__ T2, const float* __restrict__ T3,
        const float* __restrict__ W,   // K*64*64
        const float* __restrict__ bias,
        const float* __restrict__ g, const float* __restrict__ be,
        const float* __restrict__ rm, const float* __restrict__ rv,
        float* __restrict__ out) {
    __shared__ float Wl[KCHEB * HDIM * HDIM];  // 64 KB
    for (int i = threadIdx.x; i < KCHEB * HDIM * HDIM; i += 256) Wl[i] = W[i];
    __syncthreads();

    int n = blockIdx.x * 4 + (threadIdx.x >> 6);
    int h = threadIdx.x & 63;
    if (n >= N_NODES) return;

    float acc = bias[h];
    const float* Ts[KCHEB] = {T0, T1, T2, T3};
    #pragma unroll
    for (int k = 0; k < KCHEB; ++k) {
        const float* T = Ts[k] + n * HDIM;
        const float* Wk = Wl + k * HDIM * HDIM;
        #pragma unroll
        for (int i = 0; i < HDIM; ++i)
            acc = fmaf(T[i], Wk[i * HDIM + h], acc);
    }
    float sc = g[h] * rsqrtf(rv[h] + BN_EPS);
    acc = (acc - rm[h]) * sc + be[h];
    out[n * HDIM + h] = fmaxf(acc, 0.0f);
}

// ---------------------------------------------------------------- head: out = h @ headW + headB
__global__ __launch_bounds__(256) void head_kernel(
        const float* __restrict__ h, const float* __restrict__ W,  // 64x16
        const float* __restrict__ b, float* __restrict__ out) {
    __shared__ float Wl[HDIM * OCDIM];
    for (int i = threadIdx.x; i < HDIM * OCDIM; i += 256) Wl[i] = W[i];
    __syncthreads();

    int idx = blockIdx.x * 256 + threadIdx.x;
    if (idx >= N_NODES * OCDIM) return;
    int n = idx >> 4, oc = idx & 15;
    float acc = b[oc];
    const float* hr = h + n * HDIM;
    #pragma unroll
    for (int i = 0; i < HDIM; ++i)
        acc = fmaf(hr[i], Wl[i * OCDIM + oc], acc);
    out[idx] = acc;
}

// ---------------------------------------------------------------- launch
extern "C" void kernel_launch(void* const* d_in, const int* in_sizes, int n_in,
                              void* d_out, int out_size, void* d_ws, size_t ws_size,
                              hipStream_t stream) {
    const float* x     = (const float*)d_in[0];
    const int*   ei    = (const int*)  d_in[1];
    const float* W1    = (const float*)d_in[2];
    const float* bc1   = (const float*)d_in[3];
    const float* W2    = (const float*)d_in[4];
    const float* bc2   = (const float*)d_in[5];
    const float* W3    = (const float*)d_in[6];
    const float* bc3   = (const float*)d_in[7];
    const float* g1  = (const float*)d_in[8],  *be1 = (const float*)d_in[9];
    const float* rm1 = (const float*)d_in[10], *rv1 = (const float*)d_in[11];
    const float* g2  = (const float*)d_in[12], *be2 = (const float*)d_in[13];
    const float* rm2 = (const float*)d_in[14], *rv2 = (const float*)d_in[15];
    const float* g3  = (const float*)d_in[16], *be3 = (const float*)d_in[17];
    const float* rm3 = (const float*)d_in[18], *rv3 = (const float*)d_in[19];
    const float* headW = (const float*)d_in[20];
    const float* headB = (const float*)d_in[21];

    const int* src = ei;            // edge_index[0]
    const int* dst = ei + E_EDGES;  // edge_index[1]

    const size_t NH = (size_t)N_NODES * HDIM;
    float* ws   = (float*)d_ws;
    float* dinv = ws;                 // N
    float* T1   = ws + N_NODES;       // N*64
    float* T2   = T1 + NH;
    float* T3   = T2 + NH;
    float* O1   = T3 + NH;
    float* O2   = O1 + NH;

    const int n4 = (int)(NH / 4);  // float4 count for copyneg
    const int PROP_GRID = (E_EDGES + 3) / 4;
    const int CN_GRID   = (n4 + 255) / 256;
    const int CB_GRID   = (N_NODES + 3) / 4;

    // degree -> dinv (in place)
    hipMemsetAsync(dinv, 0, N_NODES * sizeof(float), stream);
    deg_kernel<<<(E_EDGES + 255) / 256, 256, 0, stream>>>(src, dinv);
    dinv_kernel<<<(N_NODES + 255) / 256, 256, 0, stream>>>(dinv);

    auto layer = [&](const float* X, const float* W, const float* bc,
                     const float* g, const float* be, const float* rm, const float* rv,
                     float* O) {
        // T1 = L X
        hipMemsetAsync(T1, 0, NH * sizeof(float), stream);
        prop_kernel<<<PROP_GRID, 256, 0, stream>>>(X, T1, src, dst, dinv, 1.0f);
        // T2 = 2 L T1 - X
        copyneg_kernel<<<CN_GRID, 256, 0, stream>>>(X, T2, n4);
        prop_kernel<<<PROP_GRID, 256, 0, stream>>>(T1, T2, src, dst, dinv, 2.0f);
        // T3 = 2 L T2 - T1
        copyneg_kernel<<<CN_GRID, 256, 0, stream>>>(T1, T3, n4);
        prop_kernel<<<PROP_GRID, 256, 0, stream>>>(T2, T3, src, dst, dinv, 2.0f);
        // O = relu(BN(sum T_k W_k + bc))
        combine_kernel<<<CB_GRID, 256, 0, stream>>>(X, T1, T2, T3, W, bc,
                                                    g, be, rm, rv, O);
    };

    layer(x,  W1, bc1, g1, be1, rm1, rv1, O1);
    layer(O1, W2, bc2, g2, be2, rm2, rv2, O2);
    layer(O2, W3, bc3, g3, be3, rm3, rv3, O1);  // O1 free again -> layer3 out

    head_kernel<<<(N_NODES * OCDIM + 255) / 256, 256, 0, stream>>>(
        O1, headW, headB, (float*)d_out);
}

// Round 2
// 1576.866 us; speedup vs baseline: 2.5216x; 2.5216x over previous
//
#include <hip/hip_runtime.h>

#define NN 100000
#define EE 1600000
#define HD 64
#define OCD 16
#define BN_EPS 1e-5f

// ================================================================ CSR build
__global__ void hist_kernel(const int* __restrict__ src, const int* __restrict__ dst,
                            int* __restrict__ cs, int* __restrict__ cd) {
    int e = blockIdx.x * 256 + threadIdx.x;
    if (e < EE) {
        atomicAdd(&cs[src[e]], 1);   // out-degree (for dinv)
        atomicAdd(&cd[dst[e]], 1);   // in-degree  (for CSR rows)
    }
}

__global__ void dinv_kernel(const int* __restrict__ cs, float* __restrict__ dinv) {
    int i = blockIdx.x * 256 + threadIdx.x;
    if (i < NN) {
        int d = cs[i];
        dinv[i] = (d > 0) ? rsqrtf((float)d) : 0.0f;
    }
}

// scan pass 1: per-block (1024-elem chunk) sums of cd
__global__ __launch_bounds__(256) void scan1_kernel(const int* __restrict__ cd,
                                                    int* __restrict__ bsum) {
    __shared__ int ws[4];
    int base = blockIdx.x * 1024;
    int t = threadIdx.x;
    int s = 0;
    #pragma unroll
    for (int j = 0; j < 4; ++j) {
        int i = base + t * 4 + j;
        if (i < NN) s += cd[i];
    }
    #pragma unroll
    for (int o = 32; o > 0; o >>= 1) s += __shfl_down(s, o);
    if ((t & 63) == 0) ws[t >> 6] = s;
    __syncthreads();
    if (t == 0) bsum[blockIdx.x] = ws[0] + ws[1] + ws[2] + ws[3];
}

// scan pass 2: exclusive scan of block sums (tiny, single thread)
__global__ void scan2_kernel(int* bsum, int nb, int* rowp) {
    if (threadIdx.x == 0 && blockIdx.x == 0) {
        int run = 0;
        for (int b = 0; b < nb; ++b) { int v = bsum[b]; bsum[b] = run; run += v; }
        rowp[NN] = run;
    }
}

// scan pass 3: per-block exclusive scan -> rowp + cursor
__global__ __launch_bounds__(256) void scan3_kernel(const int* __restrict__ cd,
                                                    const int* __restrict__ bsum,
                                                    int* __restrict__ rowp,
                                                    int* __restrict__ cursor) {
    __shared__ int tsum[256];
    int base = blockIdx.x * 1024;
    int t = threadIdx.x;
    int v[4]; int s = 0;
    #pragma unroll
    for (int j = 0; j < 4; ++j) {
        int i = base + t * 4 + j;
        v[j] = (i < NN) ? cd[i] : 0;
        s += v[j];
    }
    tsum[t] = s;
    __syncthreads();
    for (int o = 1; o < 256; o <<= 1) {
        int xv = (t >= o) ? tsum[t - o] : 0;
        __syncthreads();
        tsum[t] += xv;
        __syncthreads();
    }
    int excl = bsum[blockIdx.x] + tsum[t] - s;
    #pragma unroll
    for (int j = 0; j < 4; ++j) {
        int i = base + t * 4 + j;
        if (i < NN) { rowp[i] = excl; cursor[i] = excl; excl += v[j]; }
    }
}

__global__ void scatter_kernel(const int* __restrict__ src, const int* __restrict__ dst,
                               const float* __restrict__ dinv,
                               int* __restrict__ cursor,
                               int* __restrict__ col, float* __restrict__ ew) {
    int e = blockIdx.x * 256 + threadIdx.x;
    if (e >= EE) return;
    int s = src[e], d = dst[e];
    int pos = atomicAdd(&cursor[d], 1);
    col[pos] = s;
    ew[pos] = -dinv[s] * dinv[d];
}

// ================================================================ propagation
// out[d] = alpha * sum_{e in row d} ew[e]*x[col[e]]  + beta * prev[d]
// one 64-lane wave per dst row, lane = feature
__global__ __launch_bounds__(256) void prop_csr_kernel(
        const float* __restrict__ x, const float* __restrict__ prev,
        float* __restrict__ out,
        const int* __restrict__ rowp, const int* __restrict__ col,
        const float* __restrict__ ew, float alpha, float beta) {
    int d = blockIdx.x * 4 + (threadIdx.x >> 6);
    int lane = threadIdx.x & 63;
    if (d >= NN) return;
    int e0 = rowp[d], e1 = rowp[d + 1];
    float acc = 0.0f;
    int e = e0;
    for (; e + 1 < e1; e += 2) {
        int s0 = col[e], s1 = col[e + 1];
        float w0 = ew[e], w1 = ew[e + 1];
        float v0 = x[(size_t)s0 * HD + lane];
        float v1 = x[(size_t)s1 * HD + lane];
        acc = fmaf(w0, v0, acc);
        acc = fmaf(w1, v1, acc);
    }
    if (e < e1) {
        acc = fmaf(ew[e], x[(size_t)col[e] * HD + lane], acc);
    }
    float r = alpha * acc;
    if (prev) r = fmaf(beta, prev[(size_t)d * HD + lane], r);
    out[(size_t)d * HD + lane] = r;
}

// ================================================================ combine
// out[tile] = relu(BN(sum_k T_k[tile] @ W_k + bias)); 64 nodes x 64 h per block
__global__ __launch_bounds__(256) void combine_kernel(
        const float* __restrict__ T0, const float* __restrict__ T1,
        const float* __restrict__ T2, const float* __restrict__ T3,
        const float* __restrict__ W,   // [4][64][64]
        const float* __restrict__ bias,
        const float* __restrict__ g, const float* __restrict__ be,
        const float* __restrict__ rm, const float* __restrict__ rv,
        float* __restrict__ out) {
    __shared__ float Tl[64][68];     // +4 pad: row-stride 272B, 16B aligned
    __shared__ float Wl[64 * 64];

    int nbase = blockIdx.x * 64;
    int t = threadIdx.x;
    int h0 = (t & 15) * 4;
    int n0 = (t >> 4) * 4;

    float acc[4][4] = {{0.f}};
    const float* Ts[4] = {T0, T1, T2, T3};

    #pragma unroll
    for (int k = 0; k < 4; ++k) {
        __syncthreads();  // protect previous iteration's reads
        const float* Wk = W + k * 4096;
        for (int j = t; j < 1024; j += 256)
            ((float4*)Wl)[j] = ((const float4*)Wk)[j];
        const float* Tk = Ts[k] + (size_t)nbase * HD;
        for (int j = t; j < 1024; j += 256) {
            int r = j >> 4, c = (j & 15) * 4;
            float4 tv = make_float4(0.f, 0.f, 0.f, 0.f);
            if (nbase + r < NN) tv = *(const float4*)(Tk + r * HD + c);
            *(float4*)(&Tl[r][c]) = tv;
        }
        __syncthreads();

        #pragma unroll
        for (int i0 = 0; i0 < 64; i0 += 4) {
            float av[4][4], bv[4][4];
            #pragma unroll
            for (int j = 0; j < 4; ++j) {
                float4 a = *(const float4*)(&Tl[n0 + j][i0]);
                av[j][0] = a.x; av[j][1] = a.y; av[j][2] = a.z; av[j][3] = a.w;
            }
            #pragma unroll
            for (int p = 0; p < 4; ++p) {
                float4 b = *(const float4*)(&Wl[(i0 + p) * 64 + h0]);
                bv[p][0] = b.x; bv[p][1] = b.y; bv[p][2] = b.z; bv[p][3] = b.w;
            }
            #pragma unroll
            for (int j = 0; j < 4; ++j)
                #pragma unroll
                for (int q = 0; q < 4; ++q)
                    #pragma unroll
                    for (int p = 0; p < 4; ++p)
                        acc[j][q] = fmaf(av[j][p], bv[p][q], acc[j][q]);
        }
    }

    // epilogue: bias + BN + relu, float4 stores
    float sc[4], rmh[4], beh[4], bih[4];
    #pragma unroll
    for (int q = 0; q < 4; ++q) {
        int h = h0 + q;
        sc[q]  = g[h] * rsqrtf(rv[h] + BN_EPS);
        rmh[q] = rm[h];
        beh[q] = be[h];
        bih[q] = bias[h];
    }
    #pragma unroll
    for (int j = 0; j < 4; ++j) {
        int n = nbase + n0 + j;
        if (n >= NN) continue;
        float4 o;
        o.x = fmaxf((acc[j][0] + bih[0] - rmh[0]) * sc[0] + beh[0], 0.f);
        o.y = fmaxf((acc[j][1] + bih[1] - rmh[1]) * sc[1] + beh[1], 0.f);
        o.z = fmaxf((acc[j][2] + bih[2] - rmh[2]) * sc[2] + beh[2], 0.f);
        o.w = fmaxf((acc[j][3] + bih[3] - rmh[3]) * sc[3] + beh[3], 0.f);
        *(float4*)(&out[(size_t)n * HD + h0]) = o;
    }
}

// ================================================================ head
__global__ __launch_bounds__(256) void head_kernel(
        const float* __restrict__ h, const float* __restrict__ W,  // 64x16
        const float* __restrict__ b, float* __restrict__ out) {
    __shared__ float Wl[HD * OCD];
    for (int i = threadIdx.x; i < HD * OCD; i += 256) Wl[i] = W[i];
    __syncthreads();

    int idx = blockIdx.x * 256 + threadIdx.x;
    if (idx >= NN * OCD) return;
    int n = idx >> 4, oc = idx & 15;
    float acc = b[oc];
    const float* hr = h + (size_t)n * HD;
    #pragma unroll
    for (int i = 0; i < HD; ++i)
        acc = fmaf(hr[i], Wl[i * OCD + oc], acc);
    out[idx] = acc;
}

// ================================================================ launch
static inline size_t al256(size_t x) { return (x + 255) & ~(size_t)255; }

extern "C" void kernel_launch(void* const* d_in, const int* in_sizes, int n_in,
                              void* d_out, int out_size, void* d_ws, size_t ws_size,
                              hipStream_t stream) {
    const float* x     = (const float*)d_in[0];
    const int*   ei    = (const int*)  d_in[1];
    const float* W1    = (const float*)d_in[2];
    const float* bc1   = (const float*)d_in[3];
    const float* W2    = (const float*)d_in[4];
    const float* bc2   = (const float*)d_in[5];
    const float* W3    = (const float*)d_in[6];
    const float* bc3   = (const float*)d_in[7];
    const float* g1  = (const float*)d_in[8],  *be1 = (const float*)d_in[9];
    const float* rm1 = (const float*)d_in[10], *rv1 = (const float*)d_in[11];
    const float* g2  = (const float*)d_in[12], *be2 = (const float*)d_in[13];
    const float* rm2 = (const float*)d_in[14], *rv2 = (const float*)d_in[15];
    const float* g3  = (const float*)d_in[16], *be3 = (const float*)d_in[17];
    const float* rm3 = (const float*)d_in[18], *rv3 = (const float*)d_in[19];
    const float* headW = (const float*)d_in[20];
    const float* headB = (const float*)d_in[21];

    const int* src = ei;
    const int* dst = ei + EE;

    // ---- workspace carve-up (byte offsets, 256B aligned)
    char* w = (char*)d_ws;
    size_t off = 0;
    auto take = [&](size_t bytes) { char* p = w + off; off += al256(bytes); return p; };
    float* dinv   = (float*)take(NN * 4);
    int*   cs     = (int*)  take(NN * 4);
    int*   cd     = (int*)  take(NN * 4);
    int*   rowp   = (int*)  take((NN + 1) * 4);
    int*   cursor = (int*)  take(NN * 4);
    int*   bsum   = (int*)  take(256 * 4);
    int*   col    = (int*)  take((size_t)EE * 4);
    float* ew     = (float*)take((size_t)EE * 4);
    const size_t NH = (size_t)NN * HD;
    float* A = (float*)take(NH * 4);
    float* B = (float*)take(NH * 4);
    float* C = (float*)take(NH * 4);
    float* D = (float*)take(NH * 4);

    const int NB_SCAN = (NN + 1023) / 1024;  // 98
    const int EG = (EE + 255) / 256;         // 6250
    const int NG = (NN + 255) / 256;         // 391
    const int PROP_GRID = (NN + 3) / 4;      // 25000
    const int CB_GRID   = (NN + 63) / 64;    // 1563

    // ---- CSR build
    hipMemsetAsync(cs, 0, NN * 4, stream);
    hipMemsetAsync(cd, 0, NN * 4, stream);
    hist_kernel<<<EG, 256, 0, stream>>>(src, dst, cs, cd);
    dinv_kernel<<<NG, 256, 0, stream>>>(cs, dinv);
    scan1_kernel<<<NB_SCAN, 256, 0, stream>>>(cd, bsum);
    scan2_kernel<<<1, 64, 0, stream>>>(bsum, NB_SCAN, rowp);
    scan3_kernel<<<NB_SCAN, 256, 0, stream>>>(cd, bsum, rowp, cursor);
    scatter_kernel<<<EG, 256, 0, stream>>>(src, dst, dinv, cursor, col, ew);

    auto layer = [&](const float* X, const float* Wc, const float* bc,
                     const float* g, const float* be, const float* rm, const float* rv,
                     float* O) {
        // T1 = L X
        prop_csr_kernel<<<PROP_GRID, 256, 0, stream>>>(X, nullptr, A, rowp, col, ew, 1.0f, 0.0f);
        // T2 = 2 L T1 - X
        prop_csr_kernel<<<PROP_GRID, 256, 0, stream>>>(A, X, B, rowp, col, ew, 2.0f, -1.0f);
        // T3 = 2 L T2 - T1
        prop_csr_kernel<<<PROP_GRID, 256, 0, stream>>>(B, A, C, rowp, col, ew, 2.0f, -1.0f);
        combine_kernel<<<CB_GRID, 256, 0, stream>>>(X, A, B, C, Wc, bc, g, be, rm, rv, O);
    };

    layer(x, W1, bc1, g1, be1, rm1, rv1, D);
    layer(D, W2, bc2, g2, be2, rm2, rv2, D);   // out aliases X: per-tile safe
    layer(D, W3, bc3, g3, be3, rm3, rv3, D);

    head_kernel<<<(NN * OCD + 255) / 256, 256, 0, stream>>>(D, headW, headB, (float*)d_out);
}

// Round 3
// 1053.050 us; speedup vs baseline: 3.7758x; 1.4974x over previous
//
#include <hip/hip_runtime.h>

#define NN 100000
#define EE 1600000
#define HD 64
#define OCD 16
#define BN_EPS 1e-5f

// ================================================================ CSR build
__global__ void hist_kernel(const int* __restrict__ src, const int* __restrict__ dst,
                            int* __restrict__ cs, int* __restrict__ cd) {
    int e = blockIdx.x * 256 + threadIdx.x;
    if (e < EE) {
        atomicAdd(&cs[src[e]], 1);   // out-degree (for dinv)
        atomicAdd(&cd[dst[e]], 1);   // in-degree  (for CSR rows)
    }
}

__global__ void dinv_kernel(const int* __restrict__ cs, float* __restrict__ dinv) {
    int i = blockIdx.x * 256 + threadIdx.x;
    if (i < NN) {
        int d = cs[i];
        dinv[i] = (d > 0) ? rsqrtf((float)d) : 0.0f;
    }
}

// scan pass 1: per-block (1024-elem chunk) sums of cd
__global__ __launch_bounds__(256) void scan1_kernel(const int* __restrict__ cd,
                                                    int* __restrict__ bsum) {
    __shared__ int ws[4];
    int base = blockIdx.x * 1024;
    int t = threadIdx.x;
    int s = 0;
    #pragma unroll
    for (int j = 0; j < 4; ++j) {
        int i = base + t * 4 + j;
        if (i < NN) s += cd[i];
    }
    #pragma unroll
    for (int o = 32; o > 0; o >>= 1) s += __shfl_down(s, o);
    if ((t & 63) == 0) ws[t >> 6] = s;
    __syncthreads();
    if (t == 0) bsum[blockIdx.x] = ws[0] + ws[1] + ws[2] + ws[3];
}

// scan pass 2: exclusive scan of block sums
__global__ void scan2_kernel(int* bsum, int nb, int* rowp) {
    if (threadIdx.x == 0 && blockIdx.x == 0) {
        int run = 0;
        for (int b = 0; b < nb; ++b) { int v = bsum[b]; bsum[b] = run; run += v; }
        rowp[NN] = run;
    }
}

// scan pass 3: per-block exclusive scan -> rowp + cursor
__global__ __launch_bounds__(256) void scan3_kernel(const int* __restrict__ cd,
                                                    const int* __restrict__ bsum,
                                                    int* __restrict__ rowp,
                                                    int* __restrict__ cursor) {
    __shared__ int tsum[256];
    int base = blockIdx.x * 1024;
    int t = threadIdx.x;
    int v[4]; int s = 0;
    #pragma unroll
    for (int j = 0; j < 4; ++j) {
        int i = base + t * 4 + j;
        v[j] = (i < NN) ? cd[i] : 0;
        s += v[j];
    }
    tsum[t] = s;
    __syncthreads();
    for (int o = 1; o < 256; o <<= 1) {
        int xv = (t >= o) ? tsum[t - o] : 0;
        __syncthreads();
        tsum[t] += xv;
        __syncthreads();
    }
    int excl = bsum[blockIdx.x] + tsum[t] - s;
    #pragma unroll
    for (int j = 0; j < 4; ++j) {
        int i = base + t * 4 + j;
        if (i < NN) { rowp[i] = excl; cursor[i] = excl; excl += v[j]; }
    }
}

__global__ void scatter_kernel(const int* __restrict__ src, const int* __restrict__ dst,
                               const float* __restrict__ dinv,
                               int* __restrict__ cursor,
                               int* __restrict__ col, float* __restrict__ ew) {
    int e = blockIdx.x * 256 + threadIdx.x;
    if (e >= EE) return;
    int s = src[e], d = dst[e];
    int pos = atomicAdd(&cursor[d], 1);
    col[pos] = s;
    ew[pos] = -dinv[s] * dinv[d];
}

// ================================================================ weight folding
// Chebyshev recursion folded into powers U_k = L^k X:
//   sum_k T_k W_k = X(W0-W2) + U1(W1-3W3) + U2(2W2) + U3(4W3)
// BN folded: W'_k[i][h] *= sc[h];  bias' = (bc-rm)*sc + be
__global__ void fold_kernel(const float* __restrict__ W, const float* __restrict__ bc,
                            const float* __restrict__ g, const float* __restrict__ be,
                            const float* __restrict__ rm, const float* __restrict__ rv,
                            float* __restrict__ Wf, float* __restrict__ biasf) {
    int idx = blockIdx.x * 256 + threadIdx.x;
    if (idx >= 4096) return;
    int h = idx & 63;
    float sc = g[h] * rsqrtf(rv[h] + BN_EPS);
    float w0 = W[idx], w1 = W[4096 + idx], w2 = W[8192 + idx], w3 = W[12288 + idx];
    Wf[idx]         = (w0 - w2) * sc;
    Wf[4096 + idx]  = (w1 - 3.0f * w3) * sc;
    Wf[8192 + idx]  = (2.0f * w2) * sc;
    Wf[12288 + idx] = (4.0f * w3) * sc;
    if (idx < 64)
        biasf[idx] = (bc[idx] - rm[idx]) * g[idx] * rsqrtf(rv[idx] + BN_EPS) + be[idx];
}

// ================================================================ propagation
// out[d] = sum_{e in row d} ew[e] * x[col[e]]   (pure U_k = L U_{k-1})
// one 64-lane wave per dst row, lane = feature
__global__ __launch_bounds__(256) void prop_kernel(
        const float* __restrict__ x, float* __restrict__ out,
        const int* __restrict__ rowp, const int* __restrict__ col,
        const float* __restrict__ ew) {
    int d = blockIdx.x * 4 + (threadIdx.x >> 6);
    int lane = threadIdx.x & 63;
    if (d >= NN) return;
    int e0 = rowp[d], e1 = rowp[d + 1];
    float acc = 0.0f;
    int e = e0;
    for (; e + 3 < e1; e += 4) {
        int s0 = col[e], s1 = col[e + 1], s2 = col[e + 2], s3 = col[e + 3];
        float w0 = ew[e], w1 = ew[e + 1], w2 = ew[e + 2], w3 = ew[e + 3];
        float v0 = x[(size_t)s0 * HD + lane];
        float v1 = x[(size_t)s1 * HD + lane];
        float v2 = x[(size_t)s2 * HD + lane];
        float v3 = x[(size_t)s3 * HD + lane];
        acc = fmaf(w0, v0, acc);
        acc = fmaf(w1, v1, acc);
        acc = fmaf(w2, v2, acc);
        acc = fmaf(w3, v3, acc);
    }
    for (; e < e1; ++e)
        acc = fmaf(ew[e], x[(size_t)col[e] * HD + lane], acc);
    out[(size_t)d * HD + lane] = acc;
}

// ================================================================ combine
// out = relu(sum_k U_k @ Wf_k + biasf); optional fused head: out16 = h @ headW + headB
template<bool FUSE_HEAD>
__global__ __launch_bounds__(256, 4) void combine_kernel(
        const float* __restrict__ T0, const float* __restrict__ T1,
        const float* __restrict__ T2, const float* __restrict__ T3,
        const float* __restrict__ Wf,     // [4][64][64] folded
        const float* __restrict__ biasf,  // [64]
        float* __restrict__ out,          // N x 64 (if !FUSE_HEAD)
        const float* __restrict__ headW,  // 64 x 16
        const float* __restrict__ headB,  // 16
        float* __restrict__ out16) {      // N x 16
    __shared__ float Tl[64][68];   // +4 pad
    __shared__ float Wl[4096];

    int nbase = blockIdx.x * 64;
    int t = threadIdx.x;
    int h0 = (t & 15) * 4;
    int n0 = (t >> 4) * 4;

    float acc[4][4] = {{0.f}};
    const float* Ts[4] = {T0, T1, T2, T3};

    for (int k = 0; k < 4; ++k) {
        __syncthreads();   // protect previous iteration's LDS reads
        const float* Wk = Wf + k * 4096;
        #pragma unroll
        for (int j = 0; j < 4; ++j)
            ((float4*)Wl)[t + j * 256] = ((const float4*)Wk)[t + j * 256];
        const float* Tk = Ts[k] + (size_t)nbase * HD;
        #pragma unroll
        for (int jj = 0; jj < 4; ++jj) {
            int j = t + jj * 256;
            int r = j >> 4, c = (j & 15) * 4;
            float4 tv = make_float4(0.f, 0.f, 0.f, 0.f);
            if (nbase + r < NN) tv = *(const float4*)(Tk + r * HD + c);
            *(float4*)(&Tl[r][c]) = tv;
        }
        __syncthreads();

        #pragma unroll 4
        for (int i0 = 0; i0 < 64; i0 += 4) {
            float av[4][4], bv[4][4];
            #pragma unroll
            for (int j = 0; j < 4; ++j) {
                float4 a = *(const float4*)(&Tl[n0 + j][i0]);
                av[j][0] = a.x; av[j][1] = a.y; av[j][2] = a.z; av[j][3] = a.w;
            }
            #pragma unroll
            for (int p = 0; p < 4; ++p) {
                float4 b = *(const float4*)(&Wl[(i0 + p) * 64 + h0]);
                bv[p][0] = b.x; bv[p][1] = b.y; bv[p][2] = b.z; bv[p][3] = b.w;
            }
            #pragma unroll
            for (int j = 0; j < 4; ++j)
                #pragma unroll
                for (int q = 0; q < 4; ++q)
                    #pragma unroll
                    for (int p = 0; p < 4; ++p)
                        acc[j][q] = fmaf(av[j][p], bv[p][q], acc[j][q]);
        }
    }

    float bih[4];
    #pragma unroll
    for (int q = 0; q < 4; ++q) bih[q] = biasf[h0 + q];

    if (!FUSE_HEAD) {
        #pragma unroll
        for (int j = 0; j < 4; ++j) {
            int n = nbase + n0 + j;
            if (n >= NN) continue;
            float4 o;
            o.x = fmaxf(acc[j][0] + bih[0], 0.f);
            o.y = fmaxf(acc[j][1] + bih[1], 0.f);
            o.z = fmaxf(acc[j][2] + bih[2], 0.f);
            o.w = fmaxf(acc[j][3] + bih[3], 0.f);
            *(float4*)(&out[(size_t)n * HD + h0]) = o;
        }
    } else {
        // h tile -> LDS, then 64x16 head matmul
        __syncthreads();   // everyone done reading Tl for k=3
        #pragma unroll
        for (int j = 0; j < 4; ++j) {
            float4 o;
            o.x = fmaxf(acc[j][0] + bih[0], 0.f);
            o.y = fmaxf(acc[j][1] + bih[1], 0.f);
            o.z = fmaxf(acc[j][2] + bih[2], 0.f);
            o.w = fmaxf(acc[j][3] + bih[3], 0.f);
            *(float4*)(&Tl[n0 + j][h0]) = o;
        }
        if (t < 256) ((float4*)Wl)[t] = ((const float4*)headW)[t];  // 64x16 = 1024 floats
        __syncthreads();

        int n = t >> 2;            // 0..63
        int oc0 = (t & 3) * 4;     // 0,4,8,12
        float4 o;
        o.x = headB[oc0]; o.y = headB[oc0 + 1]; o.z = headB[oc0 + 2]; o.w = headB[oc0 + 3];
        #pragma unroll 8
        for (int i = 0; i < 64; ++i) {
            float tv = Tl[n][i];
            const float* wr = &Wl[i * OCD + oc0];
            o.x = fmaf(tv, wr[0], o.x);
            o.y = fmaf(tv, wr[1], o.y);
            o.z = fmaf(tv, wr[2], o.z);
            o.w = fmaf(tv, wr[3], o.w);
        }
        int nn = nbase + n;
        if (nn < NN) *(float4*)(&out16[(size_t)nn * OCD + oc0]) = o;
    }
}

// ================================================================ launch
static inline size_t al256(size_t x) { return (x + 255) & ~(size_t)255; }

extern "C" void kernel_launch(void* const* d_in, const int* in_sizes, int n_in,
                              void* d_out, int out_size, void* d_ws, size_t ws_size,
                              hipStream_t stream) {
    const float* x     = (const float*)d_in[0];
    const int*   ei    = (const int*)  d_in[1];
    const float* W1    = (const float*)d_in[2];
    const float* bc1   = (const float*)d_in[3];
    const float* W2    = (const float*)d_in[4];
    const float* bc2   = (const float*)d_in[5];
    const float* W3    = (const float*)d_in[6];
    const float* bc3   = (const float*)d_in[7];
    const float* g1  = (const float*)d_in[8],  *be1 = (const float*)d_in[9];
    const float* rm1 = (const float*)d_in[10], *rv1 = (const float*)d_in[11];
    const float* g2  = (const float*)d_in[12], *be2 = (const float*)d_in[13];
    const float* rm2 = (const float*)d_in[14], *rv2 = (const float*)d_in[15];
    const float* g3  = (const float*)d_in[16], *be3 = (const float*)d_in[17];
    const float* rm3 = (const float*)d_in[18], *rv3 = (const float*)d_in[19];
    const float* headW = (const float*)d_in[20];
    const float* headB = (const float*)d_in[21];

    const int* src = ei;
    const int* dst = ei + EE;

    char* w = (char*)d_ws;
    size_t off = 0;
    auto take = [&](size_t bytes) { char* p = w + off; off += al256(bytes); return p; };
    float* dinv   = (float*)take(NN * 4);
    int*   cs     = (int*)  take(NN * 4);
    int*   cd     = (int*)  take(NN * 4);
    int*   rowp   = (int*)  take((NN + 1) * 4);
    int*   cursor = (int*)  take(NN * 4);
    int*   bsum   = (int*)  take(256 * 4);
    int*   col    = (int*)  take((size_t)EE * 4);
    float* ew     = (float*)take((size_t)EE * 4);
    float* Wf1    = (float*)take(16384 * 4);
    float* Wf2    = (float*)take(16384 * 4);
    float* Wf3    = (float*)take(16384 * 4);
    float* bf1    = (float*)take(64 * 4);
    float* bf2    = (float*)take(64 * 4);
    float* bf3    = (float*)take(64 * 4);
    const size_t NH = (size_t)NN * HD;
    float* U1 = (float*)take(NH * 4);
    float* U2 = (float*)take(NH * 4);
    float* U3 = (float*)take(NH * 4);
    float* D  = (float*)take(NH * 4);

    const int NB_SCAN = (NN + 1023) / 1024;
    const int EG = (EE + 255) / 256;
    const int NG = (NN + 255) / 256;
    const int PROP_GRID = (NN + 3) / 4;
    const int CB_GRID   = (NN + 63) / 64;

    // ---- CSR build + weight folding
    hipMemsetAsync(cs, 0, NN * 4, stream);
    hipMemsetAsync(cd, 0, NN * 4, stream);
    hist_kernel<<<EG, 256, 0, stream>>>(src, dst, cs, cd);
    dinv_kernel<<<NG, 256, 0, stream>>>(cs, dinv);
    scan1_kernel<<<NB_SCAN, 256, 0, stream>>>(cd, bsum);
    scan2_kernel<<<1, 64, 0, stream>>>(bsum, NB_SCAN, rowp);
    scan3_kernel<<<NB_SCAN, 256, 0, stream>>>(cd, bsum, rowp, cursor);
    scatter_kernel<<<EG, 256, 0, stream>>>(src, dst, dinv, cursor, col, ew);
    fold_kernel<<<16, 256, 0, stream>>>(W1, bc1, g1, be1, rm1, rv1, Wf1, bf1);
    fold_kernel<<<16, 256, 0, stream>>>(W2, bc2, g2, be2, rm2, rv2, Wf2, bf2);
    fold_kernel<<<16, 256, 0, stream>>>(W3, bc3, g3, be3, rm3, rv3, Wf3, bf3);

    float* out16 = (float*)d_out;

    // ---- layer 1
    prop_kernel<<<PROP_GRID, 256, 0, stream>>>(x,  U1, rowp, col, ew);
    prop_kernel<<<PROP_GRID, 256, 0, stream>>>(U1, U2, rowp, col, ew);
    prop_kernel<<<PROP_GRID, 256, 0, stream>>>(U2, U3, rowp, col, ew);
    combine_kernel<false><<<CB_GRID, 256, 0, stream>>>(x, U1, U2, U3, Wf1, bf1,
                                                       D, nullptr, nullptr, nullptr);
    // ---- layer 2
    prop_kernel<<<PROP_GRID, 256, 0, stream>>>(D,  U1, rowp, col, ew);
    prop_kernel<<<PROP_GRID, 256, 0, stream>>>(U1, U2, rowp, col, ew);
    prop_kernel<<<PROP_GRID, 256, 0, stream>>>(U2, U3, rowp, col, ew);
    combine_kernel<false><<<CB_GRID, 256, 0, stream>>>(D, U1, U2, U3, Wf2, bf2,
                                                       D, nullptr, nullptr, nullptr);
    // ---- layer 3 (head fused)
    prop_kernel<<<PROP_GRID, 256, 0, stream>>>(D,  U1, rowp, col, ew);
    prop_kernel<<<PROP_GRID, 256, 0, stream>>>(U1, U2, rowp, col, ew);
    prop_kernel<<<PROP_GRID, 256, 0, stream>>>(U2, U3, rowp, col, ew);
    combine_kernel<true><<<CB_GRID, 256, 0, stream>>>(D, U1, U2, U3, Wf3, bf3,
                                                      nullptr, headW, headB, out16);
}

// Round 4
// 1010.644 us; speedup vs baseline: 3.9343x; 1.0420x over previous
//
#include <hip/hip_runtime.h>

#define NN 100000
#define EE 1600000
#define HD 64
#define OCD 16
#define BN_EPS 1e-5f

typedef unsigned short u16;

union f32u32 { float f; unsigned int u; };

__device__ __forceinline__ float bf2f(u16 u) {
    f32u32 c; c.u = (unsigned int)u << 16; return c.f;
}
__device__ __forceinline__ u16 f2bf(float f) {
    f32u32 c; c.f = f;
    unsigned int r = 0x7fffu + ((c.u >> 16) & 1u);   // RNE
    return (u16)((c.u + r) >> 16);
}

// ================================================================ CSR build
__global__ void hist_kernel(const int* __restrict__ src, const int* __restrict__ dst,
                            int* __restrict__ cs, int* __restrict__ cd) {
    int e = blockIdx.x * 256 + threadIdx.x;
    if (e < EE) {
        atomicAdd(&cs[src[e]], 1);   // out-degree (for dinv)
        atomicAdd(&cd[dst[e]], 1);   // in-degree  (CSR rows)
    }
}

__global__ void dinv_kernel(const int* __restrict__ cs, float* __restrict__ dinv,
                            float* __restrict__ ndsq, float* __restrict__ sdeg) {
    int i = blockIdx.x * 256 + threadIdx.x;
    if (i < NN) {
        int d = cs[i];
        float di = (d > 0) ? rsqrtf((float)d) : 0.0f;
        dinv[i] = di;
        ndsq[i] = -di * di;
        sdeg[i] = (d > 0) ? sqrtf((float)d) : 0.0f;
    }
}

__global__ __launch_bounds__(256) void scan1_kernel(const int* __restrict__ cd,
                                                    int* __restrict__ bsum) {
    __shared__ int ws[4];
    int base = blockIdx.x * 1024;
    int t = threadIdx.x;
    int s = 0;
    #pragma unroll
    for (int j = 0; j < 4; ++j) {
        int i = base + t * 4 + j;
        if (i < NN) s += cd[i];
    }
    #pragma unroll
    for (int o = 32; o > 0; o >>= 1) s += __shfl_down(s, o);
    if ((t & 63) == 0) ws[t >> 6] = s;
    __syncthreads();
    if (t == 0) bsum[blockIdx.x] = ws[0] + ws[1] + ws[2] + ws[3];
}

__global__ void scan2_kernel(int* bsum, int nb, int* rowp) {
    if (threadIdx.x == 0 && blockIdx.x == 0) {
        int run = 0;
        for (int b = 0; b < nb; ++b) { int v = bsum[b]; bsum[b] = run; run += v; }
        rowp[NN] = run;
    }
}

__global__ __launch_bounds__(256) void scan3_kernel(const int* __restrict__ cd,
                                                    const int* __restrict__ bsum,
                                                    int* __restrict__ rowp,
                                                    int* __restrict__ cursor) {
    __shared__ int tsum[256];
    int base = blockIdx.x * 1024;
    int t = threadIdx.x;
    int v[4]; int s = 0;
    #pragma unroll
    for (int j = 0; j < 4; ++j) {
        int i = base + t * 4 + j;
        v[j] = (i < NN) ? cd[i] : 0;
        s += v[j];
    }
    tsum[t] = s;
    __syncthreads();
    for (int o = 1; o < 256; o <<= 1) {
        int xv = (t >= o) ? tsum[t - o] : 0;
        __syncthreads();
        tsum[t] += xv;
        __syncthreads();
    }
    int excl = bsum[blockIdx.x] + tsum[t] - s;
    #pragma unroll
    for (int j = 0; j < 4; ++j) {
        int i = base + t * 4 + j;
        if (i < NN) { rowp[i] = excl; cursor[i] = excl; excl += v[j]; }
    }
}

__global__ void scatter_kernel(const int* __restrict__ src, const int* __restrict__ dst,
                               int* __restrict__ cursor, int* __restrict__ col) {
    int e = blockIdx.x * 256 + threadIdx.x;
    if (e >= EE) return;
    int pos = atomicAdd(&cursor[dst[e]], 1);
    col[pos] = src[e];
}

// ================================================================ weight folding
// powers: sum_k T_k W_k = X(W0-W2) + U1(W1-3W3) + U2(2W2) + U3(4W3); BN folded.
__global__ void fold_kernel(const float* __restrict__ W, const float* __restrict__ bc,
                            const float* __restrict__ g, const float* __restrict__ be,
                            const float* __restrict__ rm, const float* __restrict__ rv,
                            float* __restrict__ Wf, float* __restrict__ biasf) {
    int idx = blockIdx.x * 256 + threadIdx.x;
    if (idx >= 4096) return;
    int h = idx & 63;
    float sc = g[h] * rsqrtf(rv[h] + BN_EPS);
    float w0 = W[idx], w1 = W[4096 + idx], w2 = W[8192 + idx], w3 = W[12288 + idx];
    Wf[idx]         = (w0 - w2) * sc;
    Wf[4096 + idx]  = (w1 - 3.0f * w3) * sc;
    Wf[8192 + idx]  = (2.0f * w2) * sc;
    Wf[12288 + idx] = (4.0f * w3) * sc;
    if (idx < 64)
        biasf[idx] = (bc[idx] - rm[idx]) * g[idx] * rsqrtf(rv[idx] + BN_EPS) + be[idx];
}

// ================================================================ P0 = bf16(dinv * x)
__global__ void scale0_kernel(const float* __restrict__ x, const float* __restrict__ dinv,
                              u16* __restrict__ P0) {
    int idx = blockIdx.x * 256 + threadIdx.x;       // one float4 per thread
    if (idx >= NN * (HD / 4)) return;
    int n = idx >> 4;
    float di = dinv[n];
    float4 v = ((const float4*)x)[idx];
    u16 o[4] = { f2bf(di * v.x), f2bf(di * v.y), f2bf(di * v.z), f2bf(di * v.w) };
    *(unsigned long long*)(&P0[(size_t)idx * 4]) = *(unsigned long long*)o;
}

// ================================================================ propagation
// P_{k+1}[d] = -dinv[d]^2 * sum_{s in row d} P_k[s]   (pure gather-sum, bf16)
__global__ __launch_bounds__(256) void prop_kernel(
        const u16* __restrict__ Pin, u16* __restrict__ Pout,
        const int* __restrict__ rowp, const int* __restrict__ col,
        const float* __restrict__ ndsq) {
    int d = blockIdx.x * 4 + (threadIdx.x >> 6);
    int lane = threadIdx.x & 63;
    if (d >= NN) return;
    int e0 = rowp[d], e1 = rowp[d + 1];
    float acc = 0.0f;
    int e = e0;
    for (; e + 7 < e1; e += 8) {
        float v[8];
        #pragma unroll
        for (int j = 0; j < 8; ++j)
            v[j] = bf2f(Pin[(size_t)col[e + j] * HD + lane]);
        #pragma unroll
        for (int j = 0; j < 8; ++j) acc += v[j];
    }
    for (; e < e1; ++e)
        acc += bf2f(Pin[(size_t)col[e] * HD + lane]);
    Pout[(size_t)d * HD + lane] = f2bf(ndsq[d] * acc);
}

// ================================================================ combine
// acc = X@Wf0 + sum_{k>=1} (sdeg .* P_k)@Wf_k ; h = relu(acc+biasf)
// !FUSE_HEAD: write h (fp32) and hP = bf16(dinv.*h).  FUSE_HEAD: out16 = h@headW+headB
template<bool FUSE_HEAD>
__global__ __launch_bounds__(256, 4) void combine_kernel(
        const float* __restrict__ X,      // N x 64 fp32 (T0)
        const u16* __restrict__ P1, const u16* __restrict__ P2,
        const u16* __restrict__ P3,
        const float* __restrict__ sdeg, const float* __restrict__ dinv,
        const float* __restrict__ Wf, const float* __restrict__ biasf,
        float* __restrict__ outh, u16* __restrict__ outP,
        const float* __restrict__ headW, const float* __restrict__ headB,
        float* __restrict__ out16) {
    __shared__ float Tl[64][68];   // +4 pad
    __shared__ float Wl[4096];

    int nbase = blockIdx.x * 64;
    int t = threadIdx.x;
    int h0 = (t & 15) * 4;
    int n0 = (t >> 4) * 4;

    float acc[4][4] = {{0.f}};
    const u16* Ps[3] = {P1, P2, P3};

    for (int k = 0; k < 4; ++k) {
        __syncthreads();   // protect previous iteration's LDS reads
        const float* Wk = Wf + k * 4096;
        #pragma unroll
        for (int j = 0; j < 4; ++j)
            ((float4*)Wl)[t + j * 256] = ((const float4*)Wk)[t + j * 256];

        if (k == 0) {
            const float* Tk = X + (size_t)nbase * HD;
            #pragma unroll
            for (int jj = 0; jj < 4; ++jj) {
                int j = t + jj * 256;
                int r = j >> 4, c = (j & 15) * 4;
                float4 tv = make_float4(0.f, 0.f, 0.f, 0.f);
                if (nbase + r < NN) tv = *(const float4*)(Tk + r * HD + c);
                *(float4*)(&Tl[r][c]) = tv;
            }
        } else {
            const u16* Pk = Ps[k - 1];
            #pragma unroll
            for (int jj = 0; jj < 2; ++jj) {
                int j = t + jj * 256;           // 512 x uint4 (8 bf16 each)
                int r = j >> 3, c0 = (j & 7) * 8;
                int n = nbase + r;
                uint4 u = make_uint4(0, 0, 0, 0);
                float sd = 0.f;
                if (n < NN) {
                    u = *(const uint4*)(Pk + (size_t)n * HD + c0);
                    sd = sdeg[n];
                }
                Tl[r][c0 + 0] = sd * bf2f((u16)(u.x & 0xffff));
                Tl[r][c0 + 1] = sd * bf2f((u16)(u.x >> 16));
                Tl[r][c0 + 2] = sd * bf2f((u16)(u.y & 0xffff));
                Tl[r][c0 + 3] = sd * bf2f((u16)(u.y >> 16));
                Tl[r][c0 + 4] = sd * bf2f((u16)(u.z & 0xffff));
                Tl[r][c0 + 5] = sd * bf2f((u16)(u.z >> 16));
                Tl[r][c0 + 6] = sd * bf2f((u16)(u.w & 0xffff));
                Tl[r][c0 + 7] = sd * bf2f((u16)(u.w >> 16));
            }
        }
        __syncthreads();

        #pragma unroll 4
        for (int i0 = 0; i0 < 64; i0 += 4) {
            float av[4][4], bv[4][4];
            #pragma unroll
            for (int j = 0; j < 4; ++j) {
                float4 a = *(const float4*)(&Tl[n0 + j][i0]);
                av[j][0] = a.x; av[j][1] = a.y; av[j][2] = a.z; av[j][3] = a.w;
            }
            #pragma unroll
            for (int p = 0; p < 4; ++p) {
                float4 b = *(const float4*)(&Wl[(i0 + p) * 64 + h0]);
                bv[p][0] = b.x; bv[p][1] = b.y; bv[p][2] = b.z; bv[p][3] = b.w;
            }
            #pragma unroll
            for (int j = 0; j < 4; ++j)
                #pragma unroll
                for (int q = 0; q < 4; ++q)
                    #pragma unroll
                    for (int p = 0; p < 4; ++p)
                        acc[j][q] = fmaf(av[j][p], bv[p][q], acc[j][q]);
        }
    }

    float bih[4];
    #pragma unroll
    for (int q = 0; q < 4; ++q) bih[q] = biasf[h0 + q];

    if (!FUSE_HEAD) {
        #pragma unroll
        for (int j = 0; j < 4; ++j) {
            int n = nbase + n0 + j;
            if (n >= NN) continue;
            float4 o;
            o.x = fmaxf(acc[j][0] + bih[0], 0.f);
            o.y = fmaxf(acc[j][1] + bih[1], 0.f);
            o.z = fmaxf(acc[j][2] + bih[2], 0.f);
            o.w = fmaxf(acc[j][3] + bih[3], 0.f);
            *(float4*)(&outh[(size_t)n * HD + h0]) = o;
            float di = dinv[n];
            u16 op[4] = { f2bf(di * o.x), f2bf(di * o.y), f2bf(di * o.z), f2bf(di * o.w) };
            *(unsigned long long*)(&outP[(size_t)n * HD + h0]) = *(unsigned long long*)op;
        }
    } else {
        __syncthreads();   // done reading Tl for k=3
        #pragma unroll
        for (int j = 0; j < 4; ++j) {
            float4 o;
            o.x = fmaxf(acc[j][0] + bih[0], 0.f);
            o.y = fmaxf(acc[j][1] + bih[1], 0.f);
            o.z = fmaxf(acc[j][2] + bih[2], 0.f);
            o.w = fmaxf(acc[j][3] + bih[3], 0.f);
            *(float4*)(&Tl[n0 + j][h0]) = o;
        }
        ((float4*)Wl)[t] = ((const float4*)headW)[t & 255];  // 64x16 = 256 float4
        __syncthreads();

        int n = t >> 2;
        int oc0 = (t & 3) * 4;
        float4 o;
        o.x = headB[oc0]; o.y = headB[oc0 + 1]; o.z = headB[oc0 + 2]; o.w = headB[oc0 + 3];
        #pragma unroll 8
        for (int i = 0; i < 64; ++i) {
            float tv = Tl[n][i];
            const float* wr = &Wl[i * OCD + oc0];
            o.x = fmaf(tv, wr[0], o.x);
            o.y = fmaf(tv, wr[1], o.y);
            o.z = fmaf(tv, wr[2], o.z);
            o.w = fmaf(tv, wr[3], o.w);
        }
        int nn = nbase + n;
        if (nn < NN) *(float4*)(&out16[(size_t)nn * OCD + oc0]) = o;
    }
}

// ================================================================ launch
static inline size_t al256(size_t x) { return (x + 255) & ~(size_t)255; }

extern "C" void kernel_launch(void* const* d_in, const int* in_sizes, int n_in,
                              void* d_out, int out_size, void* d_ws, size_t ws_size,
                              hipStream_t stream) {
    const float* x     = (const float*)d_in[0];
    const int*   ei    = (const int*)  d_in[1];
    const float* W1    = (const float*)d_in[2];
    const float* bc1   = (const float*)d_in[3];
    const float* W2    = (const float*)d_in[4];
    const float* bc2   = (const float*)d_in[5];
    const float* W3    = (const float*)d_in[6];
    const float* bc3   = (const float*)d_in[7];
    const float* g1  = (const float*)d_in[8],  *be1 = (const float*)d_in[9];
    const float* rm1 = (const float*)d_in[10], *rv1 = (const float*)d_in[11];
    const float* g2  = (const float*)d_in[12], *be2 = (const float*)d_in[13];
    const float* rm2 = (const float*)d_in[14], *rv2 = (const float*)d_in[15];
    const float* g3  = (const float*)d_in[16], *be3 = (const float*)d_in[17];
    const float* rm3 = (const float*)d_in[18], *rv3 = (const float*)d_in[19];
    const float* headW = (const float*)d_in[20];
    const float* headB = (const float*)d_in[21];

    const int* src = ei;
    const int* dst = ei + EE;

    char* w = (char*)d_ws;
    size_t off = 0;
    auto take = [&](size_t bytes) { char* p = w + off; off += al256(bytes); return p; };
    float* dinv   = (float*)take(NN * 4);
    float* ndsq   = (float*)take(NN * 4);
    float* sdeg   = (float*)take(NN * 4);
    int*   cs     = (int*)  take(NN * 4);
    int*   cd     = (int*)  take(NN * 4);
    int*   rowp   = (int*)  take((NN + 1) * 4);
    int*   cursor = (int*)  take(NN * 4);
    int*   bsum   = (int*)  take(256 * 4);
    int*   col    = (int*)  take((size_t)EE * 4);
    float* Wf1    = (float*)take(16384 * 4);
    float* Wf2    = (float*)take(16384 * 4);
    float* Wf3    = (float*)take(16384 * 4);
    float* bf1    = (float*)take(64 * 4);
    float* bf2    = (float*)take(64 * 4);
    float* bf3    = (float*)take(64 * 4);
    const size_t NH = (size_t)NN * HD;
    u16* P0 = (u16*)take(NH * 2);
    u16* P1 = (u16*)take(NH * 2);
    u16* P2 = (u16*)take(NH * 2);
    u16* P3 = (u16*)take(NH * 2);
    float* D = (float*)take(NH * 4);

    const int NB_SCAN = (NN + 1023) / 1024;
    const int EG = (EE + 255) / 256;
    const int NG = (NN + 255) / 256;
    const int PROP_GRID = (NN + 3) / 4;
    const int CB_GRID   = (NN + 63) / 64;
    const int S0_GRID   = (NN * (HD / 4) + 255) / 256;

    // ---- CSR build + folding
    hipMemsetAsync(cs, 0, NN * 4, stream);
    hipMemsetAsync(cd, 0, NN * 4, stream);
    hist_kernel<<<EG, 256, 0, stream>>>(src, dst, cs, cd);
    dinv_kernel<<<NG, 256, 0, stream>>>(cs, dinv, ndsq, sdeg);
    scan1_kernel<<<NB_SCAN, 256, 0, stream>>>(cd, bsum);
    scan2_kernel<<<1, 64, 0, stream>>>(bsum, NB_SCAN, rowp);
    scan3_kernel<<<NB_SCAN, 256, 0, stream>>>(cd, bsum, rowp, cursor);
    scatter_kernel<<<EG, 256, 0, stream>>>(src, dst, cursor, col);
    fold_kernel<<<16, 256, 0, stream>>>(W1, bc1, g1, be1, rm1, rv1, Wf1, bf1);
    fold_kernel<<<16, 256, 0, stream>>>(W2, bc2, g2, be2, rm2, rv2, Wf2, bf2);
    fold_kernel<<<16, 256, 0, stream>>>(W3, bc3, g3, be3, rm3, rv3, Wf3, bf3);
    scale0_kernel<<<S0_GRID, 256, 0, stream>>>(x, dinv, P0);

    float* out16 = (float*)d_out;

    // ---- layer 1
    prop_kernel<<<PROP_GRID, 256, 0, stream>>>(P0, P1, rowp, col, ndsq);
    prop_kernel<<<PROP_GRID, 256, 0, stream>>>(P1, P2, rowp, col, ndsq);
    prop_kernel<<<PROP_GRID, 256, 0, stream>>>(P2, P3, rowp, col, ndsq);
    combine_kernel<false><<<CB_GRID, 256, 0, stream>>>(x, P1, P2, P3, sdeg, dinv,
                                                       Wf1, bf1, D, P0,
                                                       nullptr, nullptr, nullptr);
    // ---- layer 2
    prop_kernel<<<PROP_GRID, 256, 0, stream>>>(P0, P1, rowp, col, ndsq);
    prop_kernel<<<PROP_GRID, 256, 0, stream>>>(P1, P2, rowp, col, ndsq);
    prop_kernel<<<PROP_GRID, 256, 0, stream>>>(P2, P3, rowp, col, ndsq);
    combine_kernel<false><<<CB_GRID, 256, 0, stream>>>(D, P1, P2, P3, sdeg, dinv,
                                                       Wf2, bf2, D, P0,
                                                       nullptr, nullptr, nullptr);
    // ---- layer 3 (head fused)
    prop_kernel<<<PROP_GRID, 256, 0, stream>>>(P0, P1, rowp, col, ndsq);
    prop_kernel<<<PROP_GRID, 256, 0, stream>>>(P1, P2, rowp, col, ndsq);
    prop_kernel<<<PROP_GRID, 256, 0, stream>>>(P2, P3, rowp, col, ndsq);
    combine_kernel<true><<<CB_GRID, 256, 0, stream>>>(D, P1, P2, P3, sdeg, dinv,
                                                      Wf3, bf3, nullptr, nullptr,
                                                      headW, headB, out16);
}

// Round 5
// 865.837 us; speedup vs baseline: 4.5923x; 1.1672x over previous
//
#include <hip/hip_runtime.h>

#define NN 100000
#define EE 1600000
#define HD 64
#define OCD 16
#define BN_EPS 1e-5f

typedef unsigned short u16;

union f32u32 { float f; unsigned int u; };

__device__ __forceinline__ float bf2f(u16 u) {
    f32u32 c; c.u = (unsigned int)u << 16; return c.f;
}
__device__ __forceinline__ float bflo(unsigned int u) {
    f32u32 c; c.u = u << 16; return c.f;
}
__device__ __forceinline__ float bfhi(unsigned int u) {
    f32u32 c; c.u = u & 0xffff0000u; return c.f;
}
__device__ __forceinline__ u16 f2bf(float f) {
    f32u32 c; c.f = f;
    unsigned int r = 0x7fffu + ((c.u >> 16) & 1u);   // RNE
    return (u16)((c.u + r) >> 16);
}

// ================================================================ CSR build
__global__ void hist_kernel(const int* __restrict__ src, const int* __restrict__ dst,
                            int* __restrict__ cs, int* __restrict__ cd) {
    int e = blockIdx.x * 256 + threadIdx.x;
    if (e < EE) {
        atomicAdd(&cs[src[e]], 1);   // out-degree (for dinv)
        atomicAdd(&cd[dst[e]], 1);   // in-degree  (CSR rows)
    }
}

__global__ void dinv_kernel(const int* __restrict__ cs, float* __restrict__ dinv,
                            float* __restrict__ ndsq, float* __restrict__ sdeg) {
    int i = blockIdx.x * 256 + threadIdx.x;
    if (i < NN) {
        int d = cs[i];
        float di = (d > 0) ? rsqrtf((float)d) : 0.0f;
        dinv[i] = di;
        ndsq[i] = -di * di;
        sdeg[i] = (d > 0) ? sqrtf((float)d) : 0.0f;
    }
}

__global__ __launch_bounds__(256) void scan1_kernel(const int* __restrict__ cd,
                                                    int* __restrict__ bsum) {
    __shared__ int ws[4];
    int base = blockIdx.x * 1024;
    int t = threadIdx.x;
    int s = 0;
    #pragma unroll
    for (int j = 0; j < 4; ++j) {
        int i = base + t * 4 + j;
        if (i < NN) s += cd[i];
    }
    #pragma unroll
    for (int o = 32; o > 0; o >>= 1) s += __shfl_down(s, o);
    if ((t & 63) == 0) ws[t >> 6] = s;
    __syncthreads();
    if (t == 0) bsum[blockIdx.x] = ws[0] + ws[1] + ws[2] + ws[3];
}

__global__ void scan2_kernel(int* bsum, int nb, int* rowp) {
    if (threadIdx.x == 0 && blockIdx.x == 0) {
        int run = 0;
        for (int b = 0; b < nb; ++b) { int v = bsum[b]; bsum[b] = run; run += v; }
        rowp[NN] = run;
    }
}

__global__ __launch_bounds__(256) void scan3_kernel(const int* __restrict__ cd,
                                                    const int* __restrict__ bsum,
                                                    int* __restrict__ rowp,
                                                    int* __restrict__ cursor) {
    __shared__ int tsum[256];
    int base = blockIdx.x * 1024;
    int t = threadIdx.x;
    int v[4]; int s = 0;
    #pragma unroll
    for (int j = 0; j < 4; ++j) {
        int i = base + t * 4 + j;
        v[j] = (i < NN) ? cd[i] : 0;
        s += v[j];
    }
    tsum[t] = s;
    __syncthreads();
    for (int o = 1; o < 256; o <<= 1) {
        int xv = (t >= o) ? tsum[t - o] : 0;
        __syncthreads();
        tsum[t] += xv;
        __syncthreads();
    }
    int excl = bsum[blockIdx.x] + tsum[t] - s;
    #pragma unroll
    for (int j = 0; j < 4; ++j) {
        int i = base + t * 4 + j;
        if (i < NN) { rowp[i] = excl; cursor[i] = excl; excl += v[j]; }
    }
}

__global__ void scatter_kernel(const int* __restrict__ src, const int* __restrict__ dst,
                               int* __restrict__ cursor, int* __restrict__ col) {
    int e = blockIdx.x * 256 + threadIdx.x;
    if (e >= EE) return;
    int pos = atomicAdd(&cursor[dst[e]], 1);
    col[pos] = src[e];
}

// ================================================================ weight folding
__global__ void fold_kernel(const float* __restrict__ W, const float* __restrict__ bc,
                            const float* __restrict__ g, const float* __restrict__ be,
                            const float* __restrict__ rm, const float* __restrict__ rv,
                            float* __restrict__ Wf, float* __restrict__ biasf) {
    int idx = blockIdx.x * 256 + threadIdx.x;
    if (idx >= 4096) return;
    int h = idx & 63;
    float sc = g[h] * rsqrtf(rv[h] + BN_EPS);
    float w0 = W[idx], w1 = W[4096 + idx], w2 = W[8192 + idx], w3 = W[12288 + idx];
    Wf[idx]         = (w0 - w2) * sc;
    Wf[4096 + idx]  = (w1 - 3.0f * w3) * sc;
    Wf[8192 + idx]  = (2.0f * w2) * sc;
    Wf[12288 + idx] = (4.0f * w3) * sc;
    if (idx < 64)
        biasf[idx] = (bc[idx] - rm[idx]) * g[idx] * rsqrtf(rv[idx] + BN_EPS) + be[idx];
}

// ================================================================ P0 = bf16(dinv * x)
__global__ void scale0_kernel(const float* __restrict__ x, const float* __restrict__ dinv,
                              u16* __restrict__ P0) {
    int idx = blockIdx.x * 256 + threadIdx.x;       // one float4 per thread
    if (idx >= NN * (HD / 4)) return;
    int n = idx >> 4;
    float di = dinv[n];
    float4 v = ((const float4*)x)[idx];
    u16 o[4] = { f2bf(di * v.x), f2bf(di * v.y), f2bf(di * v.z), f2bf(di * v.w) };
    *(unsigned long long*)(&P0[(size_t)idx * 4]) = *(unsigned long long*)o;
}

// ================================================================ propagation
// P_{k+1}[d] = -dinv[d]^2 * sum_{s in row d} P_k[s]
// One wave per dst row. 4 x 16-lane groups: group g handles edges e0+g, e0+g+4, ...
// Lane (g,l) loads features [4l..4l+3] of row col[e] as uint2 (4 bf16).
__global__ __launch_bounds__(256) void prop_kernel(
        const u16* __restrict__ Pin, u16* __restrict__ Pout,
        const int* __restrict__ rowp, const int* __restrict__ col,
        const float* __restrict__ ndsq) {
    int d = blockIdx.x * 4 + (threadIdx.x >> 6);
    if (d >= NN) return;
    int lane = threadIdx.x & 63;
    int g = lane >> 4;        // 0..3  edge slot
    int l = lane & 15;        // 0..15 feature quad
    int e0 = rowp[d], e1 = rowp[d + 1];

    float a0 = 0.f, a1 = 0.f, a2 = 0.f, a3 = 0.f;
    int e = e0 + g;
    // 2-deep unroll: both col loads issue before the gathers
    for (; e + 4 < e1; e += 8) {
        int s0 = col[e], s1 = col[e + 4];
        uint2 u0 = *(const uint2*)(Pin + (size_t)s0 * HD + l * 4);
        uint2 u1 = *(const uint2*)(Pin + (size_t)s1 * HD + l * 4);
        a0 += bflo(u0.x); a1 += bfhi(u0.x);
        a2 += bflo(u0.y); a3 += bfhi(u0.y);
        a0 += bflo(u1.x); a1 += bfhi(u1.x);
        a2 += bflo(u1.y); a3 += bfhi(u1.y);
    }
    if (e < e1) {
        int s = col[e];
        uint2 u = *(const uint2*)(Pin + (size_t)s * HD + l * 4);
        a0 += bflo(u.x); a1 += bfhi(u.x);
        a2 += bflo(u.y); a3 += bfhi(u.y);
    }
    // reduce across the 4 edge groups (xor 16, then 32)
    a0 += __shfl_xor(a0, 16); a1 += __shfl_xor(a1, 16);
    a2 += __shfl_xor(a2, 16); a3 += __shfl_xor(a3, 16);
    a0 += __shfl_xor(a0, 32); a1 += __shfl_xor(a1, 32);
    a2 += __shfl_xor(a2, 32); a3 += __shfl_xor(a3, 32);

    if (g == 0) {
        float nd = ndsq[d];
        uint2 o;
        o.x = (unsigned int)f2bf(nd * a0) | ((unsigned int)f2bf(nd * a1) << 16);
        o.y = (unsigned int)f2bf(nd * a2) | ((unsigned int)f2bf(nd * a3) << 16);
        *(uint2*)(Pout + (size_t)d * HD + l * 4) = o;
    }
}

// ================================================================ combine
template<bool FUSE_HEAD>
__global__ __launch_bounds__(256, 4) void combine_kernel(
        const float* __restrict__ X,      // N x 64 fp32 (T0)
        const u16* __restrict__ P1, const u16* __restrict__ P2,
        const u16* __restrict__ P3,
        const float* __restrict__ sdeg, const float* __restrict__ dinv,
        const float* __restrict__ Wf, const float* __restrict__ biasf,
        float* __restrict__ outh, u16* __restrict__ outP,
        const float* __restrict__ headW, const float* __restrict__ headB,
        float* __restrict__ out16) {
    __shared__ float Tl[64][68];   // +4 pad
    __shared__ float Wl[4096];

    int nbase = blockIdx.x * 64;
    int t = threadIdx.x;
    int h0 = (t & 15) * 4;
    int n0 = (t >> 4) * 4;

    float acc[4][4] = {{0.f}};
    const u16* Ps[3] = {P1, P2, P3};

    for (int k = 0; k < 4; ++k) {
        __syncthreads();   // protect previous iteration's LDS reads
        const float* Wk = Wf + k * 4096;
        #pragma unroll
        for (int j = 0; j < 4; ++j)
            ((float4*)Wl)[t + j * 256] = ((const float4*)Wk)[t + j * 256];

        if (k == 0) {
            const float* Tk = X + (size_t)nbase * HD;
            #pragma unroll
            for (int jj = 0; jj < 4; ++jj) {
                int j = t + jj * 256;
                int r = j >> 4, c = (j & 15) * 4;
                float4 tv = make_float4(0.f, 0.f, 0.f, 0.f);
                if (nbase + r < NN) tv = *(const float4*)(Tk + r * HD + c);
                *(float4*)(&Tl[r][c]) = tv;
            }
        } else {
            const u16* Pk = Ps[k - 1];
            #pragma unroll
            for (int jj = 0; jj < 2; ++jj) {
                int j = t + jj * 256;           // 512 x uint4 (8 bf16 each)
                int r = j >> 3, c0 = (j & 7) * 8;
                int n = nbase + r;
                uint4 u = make_uint4(0, 0, 0, 0);
                float sd = 0.f;
                if (n < NN) {
                    u = *(const uint4*)(Pk + (size_t)n * HD + c0);
                    sd = sdeg[n];
                }
                Tl[r][c0 + 0] = sd * bflo(u.x);
                Tl[r][c0 + 1] = sd * bfhi(u.x);
                Tl[r][c0 + 2] = sd * bflo(u.y);
                Tl[r][c0 + 3] = sd * bfhi(u.y);
                Tl[r][c0 + 4] = sd * bflo(u.z);
                Tl[r][c0 + 5] = sd * bfhi(u.z);
                Tl[r][c0 + 6] = sd * bflo(u.w);
                Tl[r][c0 + 7] = sd * bfhi(u.w);
            }
        }
        __syncthreads();

        #pragma unroll 4
        for (int i0 = 0; i0 < 64; i0 += 4) {
            float av[4][4], bv[4][4];
            #pragma unroll
            for (int j = 0; j < 4; ++j) {
                float4 a = *(const float4*)(&Tl[n0 + j][i0]);
                av[j][0] = a.x; av[j][1] = a.y; av[j][2] = a.z; av[j][3] = a.w;
            }
            #pragma unroll
            for (int p = 0; p < 4; ++p) {
                float4 b = *(const float4*)(&Wl[(i0 + p) * 64 + h0]);
                bv[p][0] = b.x; bv[p][1] = b.y; bv[p][2] = b.z; bv[p][3] = b.w;
            }
            #pragma unroll
            for (int j = 0; j < 4; ++j)
                #pragma unroll
                for (int q = 0; q < 4; ++q)
                    #pragma unroll
                    for (int p = 0; p < 4; ++p)
                        acc[j][q] = fmaf(av[j][p], bv[p][q], acc[j][q]);
        }
    }

    float bih[4];
    #pragma unroll
    for (int q = 0; q < 4; ++q) bih[q] = biasf[h0 + q];

    if (!FUSE_HEAD) {
        #pragma unroll
        for (int j = 0; j < 4; ++j) {
            int n = nbase + n0 + j;
            if (n >= NN) continue;
            float4 o;
            o.x = fmaxf(acc[j][0] + bih[0], 0.f);
            o.y = fmaxf(acc[j][1] + bih[1], 0.f);
            o.z = fmaxf(acc[j][2] + bih[2], 0.f);
            o.w = fmaxf(acc[j][3] + bih[3], 0.f);
            *(float4*)(&outh[(size_t)n * HD + h0]) = o;
            float di = dinv[n];
            u16 op[4] = { f2bf(di * o.x), f2bf(di * o.y), f2bf(di * o.z), f2bf(di * o.w) };
            *(unsigned long long*)(&outP[(size_t)n * HD + h0]) = *(unsigned long long*)op;
        }
    } else {
        __syncthreads();   // done reading Tl for k=3
        #pragma unroll
        for (int j = 0; j < 4; ++j) {
            float4 o;
            o.x = fmaxf(acc[j][0] + bih[0], 0.f);
            o.y = fmaxf(acc[j][1] + bih[1], 0.f);
            o.z = fmaxf(acc[j][2] + bih[2], 0.f);
            o.w = fmaxf(acc[j][3] + bih[3], 0.f);
            *(float4*)(&Tl[n0 + j][h0]) = o;
        }
        ((float4*)Wl)[t] = ((const float4*)headW)[t & 255];  // 64x16 = 256 float4
        __syncthreads();

        int n = t >> 2;
        int oc0 = (t & 3) * 4;
        float4 o;
        o.x = headB[oc0]; o.y = headB[oc0 + 1]; o.z = headB[oc0 + 2]; o.w = headB[oc0 + 3];
        #pragma unroll 8
        for (int i = 0; i < 64; ++i) {
            float tv = Tl[n][i];
            const float* wr = &Wl[i * OCD + oc0];
            o.x = fmaf(tv, wr[0], o.x);
            o.y = fmaf(tv, wr[1], o.y);
            o.z = fmaf(tv, wr[2], o.z);
            o.w = fmaf(tv, wr[3], o.w);
        }
        int nn = nbase + n;
        if (nn < NN) *(float4*)(&out16[(size_t)nn * OCD + oc0]) = o;
    }
}

// ================================================================ launch
static inline size_t al256(size_t x) { return (x + 255) & ~(size_t)255; }

extern "C" void kernel_launch(void* const* d_in, const int* in_sizes, int n_in,
                              void* d_out, int out_size, void* d_ws, size_t ws_size,
                              hipStream_t stream) {
    const float* x     = (const float*)d_in[0];
    const int*   ei    = (const int*)  d_in[1];
    const float* W1    = (const float*)d_in[2];
    const float* bc1   = (const float*)d_in[3];
    const float* W2    = (const float*)d_in[4];
    const float* bc2   = (const float*)d_in[5];
    const float* W3    = (const float*)d_in[6];
    const float* bc3   = (const float*)d_in[7];
    const float* g1  = (const float*)d_in[8],  *be1 = (const float*)d_in[9];
    const float* rm1 = (const float*)d_in[10], *rv1 = (const float*)d_in[11];
    const float* g2  = (const float*)d_in[12], *be2 = (const float*)d_in[13];
    const float* rm2 = (const float*)d_in[14], *rv2 = (const float*)d_in[15];
    const float* g3  = (const float*)d_in[16], *be3 = (const float*)d_in[17];
    const float* rm3 = (const float*)d_in[18], *rv3 = (const float*)d_in[19];
    const float* headW = (const float*)d_in[20];
    const float* headB = (const float*)d_in[21];

    const int* src = ei;
    const int* dst = ei + EE;

    char* w = (char*)d_ws;
    size_t off = 0;
    auto take = [&](size_t bytes) { char* p = w + off; off += al256(bytes); return p; };
    float* dinv   = (float*)take(NN * 4);
    float* ndsq   = (float*)take(NN * 4);
    float* sdeg   = (float*)take(NN * 4);
    int*   cs     = (int*)  take(NN * 4);
    int*   cd     = (int*)  take(NN * 4);
    int*   rowp   = (int*)  take((NN + 1) * 4);
    int*   cursor = (int*)  take(NN * 4);
    int*   bsum   = (int*)  take(256 * 4);
    int*   col    = (int*)  take((size_t)EE * 4);
    float* Wf1    = (float*)take(16384 * 4);
    float* Wf2    = (float*)take(16384 * 4);
    float* Wf3    = (float*)take(16384 * 4);
    float* bf1    = (float*)take(64 * 4);
    float* bf2    = (float*)take(64 * 4);
    float* bf3    = (float*)take(64 * 4);
    const size_t NH = (size_t)NN * HD;
    u16* P0 = (u16*)take(NH * 2);
    u16* P1 = (u16*)take(NH * 2);
    u16* P2 = (u16*)take(NH * 2);
    u16* P3 = (u16*)take(NH * 2);
    float* D = (float*)take(NH * 4);

    const int NB_SCAN = (NN + 1023) / 1024;
    const int EG = (EE + 255) / 256;
    const int NG = (NN + 255) / 256;
    const int PROP_GRID = (NN + 3) / 4;
    const int CB_GRID   = (NN + 63) / 64;
    const int S0_GRID   = (NN * (HD / 4) + 255) / 256;

    // ---- CSR build + folding
    hipMemsetAsync(cs, 0, NN * 4, stream);
    hipMemsetAsync(cd, 0, NN * 4, stream);
    hist_kernel<<<EG, 256, 0, stream>>>(src, dst, cs, cd);
    dinv_kernel<<<NG, 256, 0, stream>>>(cs, dinv, ndsq, sdeg);
    scan1_kernel<<<NB_SCAN, 256, 0, stream>>>(cd, bsum);
    scan2_kernel<<<1, 64, 0, stream>>>(bsum, NB_SCAN, rowp);
    scan3_kernel<<<NB_SCAN, 256, 0, stream>>>(cd, bsum, rowp, cursor);
    scatter_kernel<<<EG, 256, 0, stream>>>(src, dst, cursor, col);
    fold_kernel<<<16, 256, 0, stream>>>(W1, bc1, g1, be1, rm1, rv1, Wf1, bf1);
    fold_kernel<<<16, 256, 0, stream>>>(W2, bc2, g2, be2, rm2, rv2, Wf2, bf2);
    fold_kernel<<<16, 256, 0, stream>>>(W3, bc3, g3, be3, rm3, rv3, Wf3, bf3);
    scale0_kernel<<<S0_GRID, 256, 0, stream>>>(x, dinv, P0);

    float* out16 = (float*)d_out;

    // ---- layer 1
    prop_kernel<<<PROP_GRID, 256, 0, stream>>>(P0, P1, rowp, col, ndsq);
    prop_kernel<<<PROP_GRID, 256, 0, stream>>>(P1, P2, rowp, col, ndsq);
    prop_kernel<<<PROP_GRID, 256, 0, stream>>>(P2, P3, rowp, col, ndsq);
    combine_kernel<false><<<CB_GRID, 256, 0, stream>>>(x, P1, P2, P3, sdeg, dinv,
                                                       Wf1, bf1, D, P0,
                                                       nullptr, nullptr, nullptr);
    // ---- layer 2
    prop_kernel<<<PROP_GRID, 256, 0, stream>>>(P0, P1, rowp, col, ndsq);
    prop_kernel<<<PROP_GRID, 256, 0, stream>>>(P1, P2, rowp, col, ndsq);
    prop_kernel<<<PROP_GRID, 256, 0, stream>>>(P2, P3, rowp, col, ndsq);
    combine_kernel<false><<<CB_GRID, 256, 0, stream>>>(D, P1, P2, P3, sdeg, dinv,
                                                       Wf2, bf2, D, P0,
                                                       nullptr, nullptr, nullptr);
    // ---- layer 3 (head fused)
    prop_kernel<<<PROP_GRID, 256, 0, stream>>>(P0, P1, rowp, col, ndsq);
    prop_kernel<<<PROP_GRID, 256, 0, stream>>>(P1, P2, rowp, col, ndsq);
    prop_kernel<<<PROP_GRID, 256, 0, stream>>>(P2, P3, rowp, col, ndsq);
    combine_kernel<true><<<CB_GRID, 256, 0, stream>>>(D, P1, P2, P3, sdeg, dinv,
                                                      Wf3, bf3, nullptr, nullptr,
                                                      headW, headB, out16);
}